// Round 3
// baseline (115.324 us; speedup 1.0000x reference)
//
#include <hip/hip_runtime.h>
#include <hip/hip_bf16.h>
#include <cstdint>

#define DEV __device__ __forceinline__

typedef __bf16 bf16_t;
typedef __bf16 bf16x8 __attribute__((ext_vector_type(8)));
typedef __bf16 bf16x4 __attribute__((ext_vector_type(4)));
typedef float  f32x4  __attribute__((ext_vector_type(4)));

constexpr float SCALE = 0.08838834764831845f; // 1/sqrt(128)

// ---- workspace byte offsets ----
constexpr size_t OFF_WSRC = 0;                      // [128][256] bf16
constexpr size_t OFF_WDST = 65536;                  // [128][256] bf16
constexpr size_t OFF_WARR = 131072;                 // [128][256] bf16
constexpr size_t OFF_W1   = 196608;                 // [256][256] bf16
constexpr size_t OFF_W2   = 327680;                 // [128][256] bf16
constexpr size_t OFF_W3T  = 393216;                 // [128][128] bf16, w3t[o][p]=w3[p][o]
constexpr size_t OFF_FT   = 425984;                 // 3 x [64 b][64 p][128 o] bf16 (src,dst,arr)
constexpr size_t OFF_GT   = OFF_FT + 3u*1048576u;   // [64 b][64 k][128 o] bf16
constexpr size_t OFF_C    = OFF_GT + 1048576u;      // [64 b][64] f32
constexpr size_t OFF_SP   = OFF_C + 16384u;         // [64 b][64 n][256 h] f32 (src_p + b1)
constexpr size_t OFF_DP   = OFF_SP + 4194304u;      // [64 b][64 m][256 h] bf16 (dst_p)
// total = 10,928,128 bytes

DEV f32x4 mfma16(bf16x8 a, bf16x8 b, f32x4 c) {
  return __builtin_amdgcn_mfma_f32_16x16x32_bf16(a, b, c, 0, 0, 0);
}

// swizzled LDS helpers: element (row,k) lives at byte row*ldaBytes + ((2k) ^ ((row&7)<<4))
DEV bf16x8 lds_ld8(const bf16_t* base, int row, int k, int ldaBytes) {
  int off = (row * ldaBytes + k * 2) ^ ((row & 7) << 4);
  return *(const bf16x8*)((const char*)base + off);
}
DEV void lds_st8(bf16_t* base, int row, int k, int ldaBytes, bf16x8 v) {
  int off = (row * ldaBytes + k * 2) ^ ((row & 7) << 4);
  *(bf16x8*)((char*)base + off) = v;
}
DEV void lds_st4(bf16_t* base, int row, int k, int ldaBytes, bf16x4 v) {
  int off = (row * ldaBytes + k * 2) ^ ((row & 7) << 4);
  *(bf16x4*)((char*)base + off) = v;
}
DEV void lds_st1(bf16_t* base, int row, int k, int ldaBytes, bf16_t v) {
  int off = (row * ldaBytes + k * 2) ^ ((row & 7) << 4);
  *(bf16_t*)((char*)base + off) = v;
}
DEV bf16x8 g_ld8(const bf16_t* p) { return *(const bf16x8*)p; }

// ======================= K0: weight prep (fp32 -> bf16, w3 transposed) ==================
__global__ __launch_bounds__(256) void k0_prep(
    const float* __restrict__ wsrc, const float* __restrict__ wdst,
    const float* __restrict__ warr, const float* __restrict__ w1,
    const float* __restrict__ w2, const float* __restrict__ w3,
    char* __restrict__ ws)
{
  int tid = blockIdx.x * 256 + threadIdx.x;
  int stride = gridDim.x * 256;
  bf16_t* osrc = (bf16_t*)(ws + OFF_WSRC);
  bf16_t* odst = (bf16_t*)(ws + OFF_WDST);
  bf16_t* oarr = (bf16_t*)(ws + OFF_WARR);
  bf16_t* ow1  = (bf16_t*)(ws + OFF_W1);
  bf16_t* ow2  = (bf16_t*)(ws + OFF_W2);
  bf16_t* ow3t = (bf16_t*)(ws + OFF_W3T);
  for (int i = tid; i < 32768; i += stride) {
    osrc[i] = (bf16_t)wsrc[i];
    odst[i] = (bf16_t)wdst[i];
    oarr[i] = (bf16_t)warr[i];
    ow2[i]  = (bf16_t)w2[i];
  }
  for (int i = tid; i < 65536; i += stride) ow1[i] = (bf16_t)w1[i];
  for (int i = tid; i < 16384; i += stride) {
    int o = i >> 7, p = i & 127;
    ow3t[i] = (bf16_t)w3[p * 128 + o];   // w3t[o][p] = w3[p][o]
  }
}

// ======================= K1: f_X^T = (w_X @ xf + b_X)^T, per (b, X) =====================
// grid = 64*3. Output fT[p][o] bf16 ([64][128] row-major, K-contiguous for downstream frags)
__global__ __launch_bounds__(256) void k1_fproj(
    const float* __restrict__ x,
    const float* __restrict__ bsrc, const float* __restrict__ bdst,
    const float* __restrict__ barr, char* __restrict__ ws)
{
  int X = blockIdx.x % 3, b = blockIdx.x / 3;
  __shared__ __attribute__((aligned(16))) bf16_t xfT[64 * 256];  // xfT[p][c], swizzled

  int t = threadIdx.x;
  const float* xb = x + (size_t)b * 16384;
  #pragma unroll
  for (int i = 0; i < 16; i++) {
    int idx4 = (i * 256 + t) * 4;           // linear in [c][p]
    int c = idx4 >> 6, p = idx4 & 63;
    f32x4 v = *(const f32x4*)(xb + idx4);
    #pragma unroll
    for (int j = 0; j < 4; j++) lds_st1(xfT, p + j, c, 512, (bf16_t)v[j]);
  }
  __syncthreads();

  const bf16_t* wb = (const bf16_t*)(ws + OFF_WSRC + (size_t)X * 65536);
  const float* bias = (X == 0) ? bsrc : ((X == 1) ? bdst : barr);
  bf16_t* fT = (bf16_t*)(ws + OFF_FT + (size_t)X * 1048576u + (size_t)b * 16384u);

  int lane = t & 63, wave = t >> 6, r16 = lane & 15, g = lane >> 4;
  f32x4 z = {0.f, 0.f, 0.f, 0.f};
  f32x4 acc[2][4];
  #pragma unroll
  for (int rf = 0; rf < 2; rf++)
    #pragma unroll
    for (int cf = 0; cf < 4; cf++) acc[rf][cf] = z;

  #pragma unroll
  for (int ks = 0; ks < 8; ks++) {
    int k = ks * 32 + g * 8;
    bf16x8 a[2], bb[4];
    #pragma unroll
    for (int rf = 0; rf < 2; rf++)
      a[rf] = g_ld8(wb + (wave * 32 + rf * 16 + r16) * 256 + k);
    #pragma unroll
    for (int cf = 0; cf < 4; cf++) bb[cf] = lds_ld8(xfT, cf * 16 + r16, k, 512);
    __builtin_amdgcn_s_setprio(1);
    #pragma unroll
    for (int rf = 0; rf < 2; rf++)
      #pragma unroll
      for (int cf = 0; cf < 4; cf++) acc[rf][cf] = mfma16(a[rf], bb[cf], acc[rf][cf]);
    __builtin_amdgcn_s_setprio(0);
  }
  #pragma unroll
  for (int rf = 0; rf < 2; rf++) {
    int o0 = wave * 32 + rf * 16 + g * 4;        // output row (o), j-consecutive
    f32x4 bv = *(const f32x4*)(bias + o0);
    #pragma unroll
    for (int cf = 0; cf < 4; cf++) {
      int p = cf * 16 + r16;                      // output col (position)
      bf16x4 pk;
      #pragma unroll
      for (int j = 0; j < 4; j++) pk[j] = (bf16_t)(acc[rf][cf][j] + bv[j]);
      *(bf16x4*)(fT + p * 128 + o0) = pk;         // fT[p][o0..o0+3]
    }
  }
}

// ======================= K2: move_logits, src_p(+b1), dst_p, GT, c =====================
// grid = 4*64 : task = bid>>6, b = bid&63
__global__ __launch_bounds__(256) void k2_pre(
    const float* __restrict__ b1, const float* __restrict__ b3,
    char* __restrict__ ws, float* __restrict__ out)
{
  int b = blockIdx.x & 63, task = blockIdx.x >> 6;
  int t = threadIdx.x, lane = t & 63, wave = t >> 6, r16 = lane & 15, g = lane >> 4;
  const bf16_t* fsrcT = (const bf16_t*)(ws + OFF_FT) + (size_t)b * 8192;
  const bf16_t* fdstT = (const bf16_t*)(ws + OFF_FT + 1048576u) + (size_t)b * 8192;
  const bf16_t* farrT = (const bf16_t*)(ws + OFF_FT + 2097152u) + (size_t)b * 8192;
  f32x4 z = {0.f, 0.f, 0.f, 0.f};

  if (task == 0) {
    // move[n][m]: A = fdstT rows m (j-consec in D), B = fsrcT row n = wave*16+r16
    f32x4 acc[4];
    #pragma unroll
    for (int cf = 0; cf < 4; cf++) acc[cf] = z;
    #pragma unroll
    for (int ks = 0; ks < 4; ks++) {
      int k = ks * 32 + g * 8;
      bf16x8 bb = g_ld8(fsrcT + (wave * 16 + r16) * 128 + k);
      #pragma unroll
      for (int cf = 0; cf < 4; cf++) {
        bf16x8 a = g_ld8(fdstT + (cf * 16 + r16) * 128 + k);
        acc[cf] = mfma16(a, bb, acc[cf]);
      }
    }
    float* ob = out + (size_t)b * 4096;
    int n = wave * 16 + r16;
    #pragma unroll
    for (int cf = 0; cf < 4; cf++) {
      f32x4 v;
      #pragma unroll
      for (int j = 0; j < 4; j++) v[j] = acc[cf][j] * SCALE;
      *(f32x4*)(ob + n * 64 + cf * 16 + g * 4) = v;
    }
  } else if (task <= 2) {
    // src_p / dst_p: A = w1-half rows h (j-consec), B = fT rows n/m
    const bf16_t* Bm = (const bf16_t*)(ws + OFF_W1) + (size_t)(wave * 64) * 256 + (task == 2 ? 128 : 0);
    const bf16_t* A = (task == 1) ? fsrcT : fdstT;
    f32x4 acc[4][4];
    #pragma unroll
    for (int cf = 0; cf < 4; cf++)
      #pragma unroll
      for (int rf = 0; rf < 4; rf++) acc[cf][rf] = z;
    #pragma unroll
    for (int ks = 0; ks < 4; ks++) {
      int k = ks * 32 + g * 8;
      bf16x8 aw[4], bb[4];
      #pragma unroll
      for (int cf = 0; cf < 4; cf++) aw[cf] = g_ld8(Bm + (cf * 16 + r16) * 256 + k);
      #pragma unroll
      for (int rf = 0; rf < 4; rf++) bb[rf] = g_ld8(A + (rf * 16 + r16) * 128 + k);
      __builtin_amdgcn_s_setprio(1);
      #pragma unroll
      for (int cf = 0; cf < 4; cf++)
        #pragma unroll
        for (int rf = 0; rf < 4; rf++) acc[cf][rf] = mfma16(aw[cf], bb[rf], acc[cf][rf]);
      __builtin_amdgcn_s_setprio(0);
    }
    if (task == 1) {
      float* sp = (float*)(ws + OFF_SP) + (size_t)b * 16384;
      #pragma unroll
      for (int cf = 0; cf < 4; cf++) {
        int h0 = wave * 64 + cf * 16 + g * 4;
        f32x4 bv = *(const f32x4*)(b1 + h0);
        #pragma unroll
        for (int rf = 0; rf < 4; rf++) {
          int n = rf * 16 + r16;
          *(f32x4*)(sp + n * 256 + h0) = acc[cf][rf] + bv;
        }
      }
    } else {
      bf16_t* dpo = (bf16_t*)(ws + OFF_DP) + (size_t)b * 16384;
      #pragma unroll
      for (int cf = 0; cf < 4; cf++) {
        int h0 = wave * 64 + cf * 16 + g * 4;
        #pragma unroll
        for (int rf = 0; rf < 4; rf++) {
          int m = rf * 16 + r16;
          bf16x4 pk;
          #pragma unroll
          for (int j = 0; j < 4; j++) pk[j] = (bf16_t)acc[cf][rf][j];
          *(bf16x4*)(dpo + m * 256 + h0) = pk;
        }
      }
    }
  } else {
    // GT[k][o] = scale * sum_p w3t[o][p]*farrT[k][p]; wave covers o in [32w,32w+32)
    const bf16_t* A = (const bf16_t*)(ws + OFF_W3T) + (size_t)(wave * 32) * 128;
    f32x4 acc[2][4];
    #pragma unroll
    for (int rf = 0; rf < 2; rf++)
      #pragma unroll
      for (int cf = 0; cf < 4; cf++) acc[rf][cf] = z;
    #pragma unroll
    for (int ks = 0; ks < 4; ks++) {
      int k = ks * 32 + g * 8;
      bf16x8 a[2], bb[4];
      #pragma unroll
      for (int rf = 0; rf < 2; rf++) a[rf] = g_ld8(A + (rf * 16 + r16) * 128 + k);
      #pragma unroll
      for (int cf = 0; cf < 4; cf++) bb[cf] = g_ld8(farrT + (cf * 16 + r16) * 128 + k);
      #pragma unroll
      for (int rf = 0; rf < 2; rf++)
        #pragma unroll
        for (int cf = 0; cf < 4; cf++) acc[rf][cf] = mfma16(a[rf], bb[cf], acc[rf][cf]);
    }
    bf16_t* GT = (bf16_t*)(ws + OFF_GT) + (size_t)b * 8192;
    #pragma unroll
    for (int rf = 0; rf < 2; rf++) {
      int o0 = wave * 32 + rf * 16 + g * 4;
      #pragma unroll
      for (int cf = 0; cf < 4; cf++) {
        int kc = cf * 16 + r16;
        bf16x4 pk;
        #pragma unroll
        for (int j = 0; j < 4; j++) pk[j] = (bf16_t)(acc[rf][cf][j] * SCALE);
        *(bf16x4*)(GT + kc * 128 + o0) = pk;
      }
    }
    if (t < 64) {  // c[k] = scale * sum_p b3[p] * f_arr[p][k]
      float s = 0.f;
      for (int p = 0; p < 128; p++) s += b3[p] * (float)farrT[t * 128 + p];
      ((float*)(ws + OFF_C))[b * 64 + t] = s * SCALE;
    }
  }
}

// ======================= K3: per (b,n): h1 -> h2 -> arrow ==============================
// grid = 64*64, 256 threads (4 waves), LDS = 32KB (h2 aliased into h1).
// All weight fragments (w2, GT) + dp chunks register-prefetched at entry: the GEMM loops
// touch only LDS + registers. __launch_bounds__(256,3) gives the allocator ~168 VGPRs.
__global__ __launch_bounds__(256, 3) void k3_main(
    const float* __restrict__ b2, const char* __restrict__ ws, float* __restrict__ out)
{
  int p = blockIdx.x;
  int l = (p & 7) * 512 + (p >> 3);          // XCD-chunked: same-b blocks share an XCD L2
  int b = l >> 6, n = l & 63;
  __shared__ __attribute__((aligned(16))) bf16_t h1[64 * 256];  // swizzled, ldaBytes=512
  bf16_t* h2 = h1;                                              // aliased, ldaBytes=256 (16KB)
  int t = threadIdx.x, lane = t & 63, wave = t >> 6, r16 = lane & 15, g = lane >> 4;

  const bf16_t* dp = (const bf16_t*)(ws + OFF_DP) + (size_t)b * 16384;
  const float*  sp = (const float*)(ws + OFF_SP) + ((size_t)b * 64 + n) * 256;
  const bf16_t* w2b = (const bf16_t*)(ws + OFF_W2);
  const bf16_t* GTb = (const bf16_t*)(ws + OFF_GT) + (size_t)b * 8192;

  // ---- entry prefetch: everything the GEMMs need, issued as one burst ----
  int m_ = t >> 2, q = t & 3;
  bf16x8 dpv[8];
  #pragma unroll
  for (int c8 = 0; c8 < 8; c8++)
    dpv[c8] = *(const bf16x8*)(dp + m_ * 256 + q * 64 + c8 * 8);
  bf16x8 w2r[2][8];
  #pragma unroll
  for (int cf = 0; cf < 2; cf++)
    #pragma unroll
    for (int ks = 0; ks < 8; ks++)
      w2r[cf][ks] = g_ld8(w2b + (wave * 32 + cf * 16 + r16) * 256 + ks * 32 + g * 8);
  bf16x8 gtr[4];
  #pragma unroll
  for (int ks = 0; ks < 4; ks++)
    gtr[ks] = g_ld8(GTb + (wave * 16 + r16) * 128 + ks * 32 + g * 8);
  f32x4 b2v[2];
  #pragma unroll
  for (int cf = 0; cf < 2; cf++) b2v[cf] = *(const f32x4*)(b2 + wave * 32 + cf * 16 + g * 4);
  f32x4 cvv = *(const f32x4*)((const float*)(ws + OFF_C) + b * 64 + wave * 16 + g * 4);

  // ---- h1 build: h1[m][k] = relu(sp[k] + dp[m][k]) ----
  #pragma unroll
  for (int c8 = 0; c8 < 8; c8++) {
    int k = q * 64 + c8 * 8;
    f32x4 s0 = *(const f32x4*)(sp + k);
    f32x4 s1 = *(const f32x4*)(sp + k + 4);
    bf16x8 hv;
    #pragma unroll
    for (int j = 0; j < 8; j++) {
      float v = (float)dpv[c8][j] + (j < 4 ? s0[j] : s1[j - 4]);
      hv[j] = (bf16_t)fmaxf(v, 0.f);
    }
    lds_st8(h1, m_, k, 512, hv);
  }
  __syncthreads();

  // ---- GEMM1: h2[m][o] = relu(sum_k h1[m][k]*w2[o][k] + b2[o]) ----
  // A = w2 regs (rows o, j-consec in D) ; B = h1 LDS (rows m)
  f32x4 z = {0.f, 0.f, 0.f, 0.f};
  f32x4 acc[2][4];
  #pragma unroll
  for (int cf = 0; cf < 2; cf++)
    #pragma unroll
    for (int rf = 0; rf < 4; rf++) acc[cf][rf] = z;
  #pragma unroll
  for (int ks = 0; ks < 8; ks++) {
    int k = ks * 32 + g * 8;
    bf16x8 bb[4];
    #pragma unroll
    for (int rf = 0; rf < 4; rf++) bb[rf] = lds_ld8(h1, rf * 16 + r16, k, 512);
    __builtin_amdgcn_s_setprio(1);
    #pragma unroll
    for (int cf = 0; cf < 2; cf++)
      #pragma unroll
      for (int rf = 0; rf < 4; rf++) acc[cf][rf] = mfma16(w2r[cf][ks], bb[rf], acc[cf][rf]);
    __builtin_amdgcn_s_setprio(0);
  }
  __syncthreads();   // all waves done READING h1 before h2 overwrites it

  #pragma unroll
  for (int cf = 0; cf < 2; cf++) {
    int o0 = wave * 32 + cf * 16 + g * 4;
    #pragma unroll
    for (int rf = 0; rf < 4; rf++) {
      int m = rf * 16 + r16;
      bf16x4 pk;
      #pragma unroll
      for (int j = 0; j < 4; j++) pk[j] = (bf16_t)fmaxf(acc[cf][rf][j] + b2v[cf][j], 0.f);
      lds_st4(h2, m, o0, 256, pk);
    }
  }
  __syncthreads();

  // ---- GEMM3': arrow[m][kc] = sum_o h2[m][o]*GT[kc][o] + c[kc] ----
  // A = GT regs (rows kc, j-consec in D) ; B = h2 LDS (rows m)
  f32x4 acc2[4];
  #pragma unroll
  for (int rf = 0; rf < 4; rf++) acc2[rf] = z;
  #pragma unroll
  for (int ks = 0; ks < 4; ks++) {
    int k = ks * 32 + g * 8;
    __builtin_amdgcn_s_setprio(1);
    #pragma unroll
    for (int rf = 0; rf < 4; rf++) {
      bf16x8 bb = lds_ld8(h2, rf * 16 + r16, k, 256);
      acc2[rf] = mfma16(gtr[ks], bb, acc2[rf]);
    }
    __builtin_amdgcn_s_setprio(0);
  }
  int kc0 = wave * 16 + g * 4;
  float* ob = out + 262144u + ((size_t)(b * 64 + n)) * 4096u;
  #pragma unroll
  for (int rf = 0; rf < 4; rf++) {
    int m = rf * 16 + r16;
    *(f32x4*)(ob + m * 64 + kc0) = acc2[rf] + cvv;
  }
}

// ======================= launch ========================================================
extern "C" void kernel_launch(void* const* d_in, const int* in_sizes, int n_in,
                              void* d_out, int out_size, void* d_ws, size_t ws_size,
                              hipStream_t stream) {
  (void)in_sizes; (void)n_in; (void)out_size; (void)ws_size;
  const float* x    = (const float*)d_in[0];
  const float* wsrc = (const float*)d_in[1];
  const float* bsrc = (const float*)d_in[2];
  const float* wdst = (const float*)d_in[3];
  const float* bdst = (const float*)d_in[4];
  const float* warr = (const float*)d_in[5];
  const float* barr = (const float*)d_in[6];
  const float* w1   = (const float*)d_in[7];
  const float* b1   = (const float*)d_in[8];
  const float* w2   = (const float*)d_in[9];
  const float* b2   = (const float*)d_in[10];
  const float* w3   = (const float*)d_in[11];
  const float* b3   = (const float*)d_in[12];
  char* ws = (char*)d_ws;
  float* out = (float*)d_out;

  hipLaunchKernelGGL(k0_prep, dim3(64), dim3(256), 0, stream, wsrc, wdst, warr, w1, w2, w3, ws);
  hipLaunchKernelGGL(k1_fproj, dim3(192), dim3(256), 0, stream, x, bsrc, bdst, barr, ws);
  hipLaunchKernelGGL(k2_pre, dim3(256), dim3(256), 0, stream, b1, b3, ws, out);
  hipLaunchKernelGGL(k3_main, dim3(4096), dim3(256), 0, stream, b2, ws, out);
}

// Round 4
// 66.227 us; speedup vs baseline: 1.7413x; 1.7413x over previous
//
#include <hip/hip_runtime.h>
#include <hip/hip_bf16.h>
#include <cstdint>

#define DEV __device__ __forceinline__

typedef __bf16 bf16_t;
typedef __bf16 bf16x8 __attribute__((ext_vector_type(8)));
typedef __bf16 bf16x4 __attribute__((ext_vector_type(4)));
typedef float  f32x4  __attribute__((ext_vector_type(4)));

constexpr float SCALE = 0.08838834764831845f; // 1/sqrt(128)

// ---- workspace byte offsets ----
constexpr size_t OFF_WSRC = 0;                      // [128][256] bf16
constexpr size_t OFF_WDST = 65536;                  // [128][256] bf16
constexpr size_t OFF_WARR = 131072;                 // [128][256] bf16
constexpr size_t OFF_W1   = 196608;                 // [256][256] bf16
constexpr size_t OFF_W2   = 327680;                 // [128][256] bf16
constexpr size_t OFF_W3T  = 393216;                 // [128][128] bf16, w3t[o][p]=w3[p][o]
constexpr size_t OFF_FT   = 425984;                 // 3 x [64 b][64 p][128 o] bf16 (src,dst,arr)
constexpr size_t OFF_GT   = OFF_FT + 3u*1048576u;   // [64 b][64 k][128 o] bf16
constexpr size_t OFF_C    = OFF_GT + 1048576u;      // [64 b][64] f32
constexpr size_t OFF_SP   = OFF_C + 16384u;         // [64 b][64 n][256 h] f32 (src_p + b1)
constexpr size_t OFF_DP   = OFF_SP + 4194304u;      // [64 b][64 m][256 h] bf16 (dst_p)
// total = 10,928,128 bytes

DEV f32x4 mfma16(bf16x8 a, bf16x8 b, f32x4 c) {
  return __builtin_amdgcn_mfma_f32_16x16x32_bf16(a, b, c, 0, 0, 0);
}

// swizzled LDS helpers: element (row,k) lives at byte row*ldaBytes + ((2k) ^ ((row&7)<<4))
DEV bf16x8 lds_ld8(const bf16_t* base, int row, int k, int ldaBytes) {
  int off = (row * ldaBytes + k * 2) ^ ((row & 7) << 4);
  return *(const bf16x8*)((const char*)base + off);
}
DEV void lds_st8(bf16_t* base, int row, int k, int ldaBytes, bf16x8 v) {
  int off = (row * ldaBytes + k * 2) ^ ((row & 7) << 4);
  *(bf16x8*)((char*)base + off) = v;
}
DEV void lds_st4(bf16_t* base, int row, int k, int ldaBytes, bf16x4 v) {
  int off = (row * ldaBytes + k * 2) ^ ((row & 7) << 4);
  *(bf16x4*)((char*)base + off) = v;
}
DEV void lds_st1(bf16_t* base, int row, int k, int ldaBytes, bf16_t v) {
  int off = (row * ldaBytes + k * 2) ^ ((row & 7) << 4);
  *(bf16_t*)((char*)base + off) = v;
}
DEV bf16x8 g_ld8(const bf16_t* p) { return *(const bf16x8*)p; }

// ======================= K0: weight prep (fp32 -> bf16, w3 transposed) ==================
__global__ __launch_bounds__(256) void k0_prep(
    const float* __restrict__ wsrc, const float* __restrict__ wdst,
    const float* __restrict__ warr, const float* __restrict__ w1,
    const float* __restrict__ w2, const float* __restrict__ w3,
    char* __restrict__ ws)
{
  int tid = blockIdx.x * 256 + threadIdx.x;
  int stride = gridDim.x * 256;
  bf16_t* osrc = (bf16_t*)(ws + OFF_WSRC);
  bf16_t* odst = (bf16_t*)(ws + OFF_WDST);
  bf16_t* oarr = (bf16_t*)(ws + OFF_WARR);
  bf16_t* ow1  = (bf16_t*)(ws + OFF_W1);
  bf16_t* ow2  = (bf16_t*)(ws + OFF_W2);
  bf16_t* ow3t = (bf16_t*)(ws + OFF_W3T);
  for (int i = tid; i < 32768; i += stride) {
    osrc[i] = (bf16_t)wsrc[i];
    odst[i] = (bf16_t)wdst[i];
    oarr[i] = (bf16_t)warr[i];
    ow2[i]  = (bf16_t)w2[i];
  }
  for (int i = tid; i < 65536; i += stride) ow1[i] = (bf16_t)w1[i];
  for (int i = tid; i < 16384; i += stride) {
    int o = i >> 7, p = i & 127;
    ow3t[i] = (bf16_t)w3[p * 128 + o];   // w3t[o][p] = w3[p][o]
  }
}

// ======================= K1: f_X^T = (w_X @ xf + b_X)^T, per (b, X) =====================
// grid = 64*3. Output fT[p][o] bf16 ([64][128] row-major, K-contiguous for downstream frags)
__global__ __launch_bounds__(256) void k1_fproj(
    const float* __restrict__ x,
    const float* __restrict__ bsrc, const float* __restrict__ bdst,
    const float* __restrict__ barr, char* __restrict__ ws)
{
  int X = blockIdx.x % 3, b = blockIdx.x / 3;
  __shared__ __attribute__((aligned(16))) bf16_t xfT[64 * 256];  // xfT[p][c], swizzled

  int t = threadIdx.x;
  const float* xb = x + (size_t)b * 16384;
  #pragma unroll
  for (int i = 0; i < 16; i++) {
    int idx4 = (i * 256 + t) * 4;           // linear in [c][p]
    int c = idx4 >> 6, p = idx4 & 63;
    f32x4 v = *(const f32x4*)(xb + idx4);
    #pragma unroll
    for (int j = 0; j < 4; j++) lds_st1(xfT, p + j, c, 512, (bf16_t)v[j]);
  }
  __syncthreads();

  const bf16_t* wb = (const bf16_t*)(ws + OFF_WSRC + (size_t)X * 65536);
  const float* bias = (X == 0) ? bsrc : ((X == 1) ? bdst : barr);
  bf16_t* fT = (bf16_t*)(ws + OFF_FT + (size_t)X * 1048576u + (size_t)b * 16384u);

  int lane = t & 63, wave = t >> 6, r16 = lane & 15, g = lane >> 4;
  f32x4 z = {0.f, 0.f, 0.f, 0.f};
  f32x4 acc[2][4];
  #pragma unroll
  for (int rf = 0; rf < 2; rf++)
    #pragma unroll
    for (int cf = 0; cf < 4; cf++) acc[rf][cf] = z;

  #pragma unroll
  for (int ks = 0; ks < 8; ks++) {
    int k = ks * 32 + g * 8;
    bf16x8 a[2], bb[4];
    #pragma unroll
    for (int rf = 0; rf < 2; rf++)
      a[rf] = g_ld8(wb + (wave * 32 + rf * 16 + r16) * 256 + k);
    #pragma unroll
    for (int cf = 0; cf < 4; cf++) bb[cf] = lds_ld8(xfT, cf * 16 + r16, k, 512);
    __builtin_amdgcn_s_setprio(1);
    #pragma unroll
    for (int rf = 0; rf < 2; rf++)
      #pragma unroll
      for (int cf = 0; cf < 4; cf++) acc[rf][cf] = mfma16(a[rf], bb[cf], acc[rf][cf]);
    __builtin_amdgcn_s_setprio(0);
  }
  #pragma unroll
  for (int rf = 0; rf < 2; rf++) {
    int o0 = wave * 32 + rf * 16 + g * 4;        // output row (o), j-consecutive
    f32x4 bv = *(const f32x4*)(bias + o0);
    #pragma unroll
    for (int cf = 0; cf < 4; cf++) {
      int p = cf * 16 + r16;                      // output col (position)
      bf16x4 pk;
      #pragma unroll
      for (int j = 0; j < 4; j++) pk[j] = (bf16_t)(acc[rf][cf][j] + bv[j]);
      *(bf16x4*)(fT + p * 128 + o0) = pk;         // fT[p][o0..o0+3]
    }
  }
}

// ======================= K2: move_logits, src_p(+b1), dst_p, GT, c =====================
// grid = 4*64 : task = bid>>6, b = bid&63
__global__ __launch_bounds__(256) void k2_pre(
    const float* __restrict__ b1, const float* __restrict__ b3,
    char* __restrict__ ws, float* __restrict__ out)
{
  int b = blockIdx.x & 63, task = blockIdx.x >> 6;
  int t = threadIdx.x, lane = t & 63, wave = t >> 6, r16 = lane & 15, g = lane >> 4;
  const bf16_t* fsrcT = (const bf16_t*)(ws + OFF_FT) + (size_t)b * 8192;
  const bf16_t* fdstT = (const bf16_t*)(ws + OFF_FT + 1048576u) + (size_t)b * 8192;
  const bf16_t* farrT = (const bf16_t*)(ws + OFF_FT + 2097152u) + (size_t)b * 8192;
  f32x4 z = {0.f, 0.f, 0.f, 0.f};

  if (task == 0) {
    // move[n][m]: A = fdstT rows m (j-consec in D), B = fsrcT row n = wave*16+r16
    f32x4 acc[4];
    #pragma unroll
    for (int cf = 0; cf < 4; cf++) acc[cf] = z;
    #pragma unroll
    for (int ks = 0; ks < 4; ks++) {
      int k = ks * 32 + g * 8;
      bf16x8 bb = g_ld8(fsrcT + (wave * 16 + r16) * 128 + k);
      #pragma unroll
      for (int cf = 0; cf < 4; cf++) {
        bf16x8 a = g_ld8(fdstT + (cf * 16 + r16) * 128 + k);
        acc[cf] = mfma16(a, bb, acc[cf]);
      }
    }
    float* ob = out + (size_t)b * 4096;
    int n = wave * 16 + r16;
    #pragma unroll
    for (int cf = 0; cf < 4; cf++) {
      f32x4 v;
      #pragma unroll
      for (int j = 0; j < 4; j++) v[j] = acc[cf][j] * SCALE;
      *(f32x4*)(ob + n * 64 + cf * 16 + g * 4) = v;
    }
  } else if (task <= 2) {
    // src_p / dst_p: A = w1-half rows h (j-consec), B = fT rows n/m
    const bf16_t* Bm = (const bf16_t*)(ws + OFF_W1) + (size_t)(wave * 64) * 256 + (task == 2 ? 128 : 0);
    const bf16_t* A = (task == 1) ? fsrcT : fdstT;
    f32x4 acc[4][4];
    #pragma unroll
    for (int cf = 0; cf < 4; cf++)
      #pragma unroll
      for (int rf = 0; rf < 4; rf++) acc[cf][rf] = z;
    #pragma unroll
    for (int ks = 0; ks < 4; ks++) {
      int k = ks * 32 + g * 8;
      bf16x8 aw[4], bb[4];
      #pragma unroll
      for (int cf = 0; cf < 4; cf++) aw[cf] = g_ld8(Bm + (cf * 16 + r16) * 256 + k);
      #pragma unroll
      for (int rf = 0; rf < 4; rf++) bb[rf] = g_ld8(A + (rf * 16 + r16) * 128 + k);
      __builtin_amdgcn_s_setprio(1);
      #pragma unroll
      for (int cf = 0; cf < 4; cf++)
        #pragma unroll
        for (int rf = 0; rf < 4; rf++) acc[cf][rf] = mfma16(aw[cf], bb[rf], acc[cf][rf]);
      __builtin_amdgcn_s_setprio(0);
    }
    if (task == 1) {
      float* sp = (float*)(ws + OFF_SP) + (size_t)b * 16384;
      #pragma unroll
      for (int cf = 0; cf < 4; cf++) {
        int h0 = wave * 64 + cf * 16 + g * 4;
        f32x4 bv = *(const f32x4*)(b1 + h0);
        #pragma unroll
        for (int rf = 0; rf < 4; rf++) {
          int n = rf * 16 + r16;
          *(f32x4*)(sp + n * 256 + h0) = acc[cf][rf] + bv;
        }
      }
    } else {
      bf16_t* dpo = (bf16_t*)(ws + OFF_DP) + (size_t)b * 16384;
      #pragma unroll
      for (int cf = 0; cf < 4; cf++) {
        int h0 = wave * 64 + cf * 16 + g * 4;
        #pragma unroll
        for (int rf = 0; rf < 4; rf++) {
          int m = rf * 16 + r16;
          bf16x4 pk;
          #pragma unroll
          for (int j = 0; j < 4; j++) pk[j] = (bf16_t)acc[cf][rf][j];
          *(bf16x4*)(dpo + m * 256 + h0) = pk;
        }
      }
    }
  } else {
    // GT[k][o] = scale * sum_p w3t[o][p]*farrT[k][p]; wave covers o in [32w,32w+32)
    const bf16_t* A = (const bf16_t*)(ws + OFF_W3T) + (size_t)(wave * 32) * 128;
    f32x4 acc[2][4];
    #pragma unroll
    for (int rf = 0; rf < 2; rf++)
      #pragma unroll
      for (int cf = 0; cf < 4; cf++) acc[rf][cf] = z;
    #pragma unroll
    for (int ks = 0; ks < 4; ks++) {
      int k = ks * 32 + g * 8;
      bf16x8 a[2], bb[4];
      #pragma unroll
      for (int rf = 0; rf < 2; rf++) a[rf] = g_ld8(A + (rf * 16 + r16) * 128 + k);
      #pragma unroll
      for (int cf = 0; cf < 4; cf++) bb[cf] = g_ld8(farrT + (cf * 16 + r16) * 128 + k);
      #pragma unroll
      for (int rf = 0; rf < 2; rf++)
        #pragma unroll
        for (int cf = 0; cf < 4; cf++) acc[rf][cf] = mfma16(a[rf], bb[cf], acc[rf][cf]);
    }
    bf16_t* GT = (bf16_t*)(ws + OFF_GT) + (size_t)b * 8192;
    #pragma unroll
    for (int rf = 0; rf < 2; rf++) {
      int o0 = wave * 32 + rf * 16 + g * 4;
      #pragma unroll
      for (int cf = 0; cf < 4; cf++) {
        int kc = cf * 16 + r16;
        bf16x4 pk;
        #pragma unroll
        for (int j = 0; j < 4; j++) pk[j] = (bf16_t)(acc[rf][cf][j] * SCALE);
        *(bf16x4*)(GT + kc * 128 + o0) = pk;
      }
    }
    if (t < 64) {  // c[k] = scale * sum_p b3[p] * f_arr[p][k]
      float s = 0.f;
      for (int p = 0; p < 128; p++) s += b3[p] * (float)farrT[t * 128 + p];
      ((float*)(ws + OFF_C))[b * 64 + t] = s * SCALE;
    }
  }
}

// ======================= K3: persistent per-(b, n-quarter) block =======================
// grid = 256 (1 block/CU, one generation), 512 threads (8 waves). Each block does 16 n's.
// n-invariant operands hoisted to registers with 16x reuse: w2 frags (128 VGPR), GT, dp,
// b2, c. sp tile staged in LDS once. Per n: [build h1(n+1) | GEMM1(n) | h2write(n)]
// -> ONE barrier -> [GEMM3(n) + stores], with double-buffered h1/h2 (race-free: every
// buffer's writes complete before the barrier that precedes its reads).
__global__ __launch_bounds__(512, 2) void k3_main(
    const float* __restrict__ b2, const char* __restrict__ ws, float* __restrict__ out)
{
  int p = blockIdx.x;
  int l = (p & 7) * 32 + (p >> 3);     // XCD c handles b in [c*8, c*8+8)
  int b = l >> 2, nq = l & 3;          // nq: which 16-row n-quarter

  __shared__ __attribute__((aligned(16))) bf16_t h1[2][64 * 256]; // 2x32KB, swizzled lda 512
  __shared__ __attribute__((aligned(16))) bf16_t h2[2][64 * 128]; // 2x16KB, swizzled lda 256
  __shared__ __attribute__((aligned(16))) float  spL[16 * 256];   // 16KB

  int t = threadIdx.x, lane = t & 63, w = t >> 6, r16 = lane & 15, g = lane >> 4;
  int mt = w & 3;     // GEMM1 m-tile / build m-tile / GEMM3 kc-tile
  int mh = w >> 2;    // GEMM1 o-half / build k-half / GEMM3 m-half

  const bf16_t* dp  = (const bf16_t*)(ws + OFF_DP) + (size_t)b * 16384;
  const float*  spg = (const float*)(ws + OFF_SP) + ((size_t)b * 64 + nq * 16) * 256;
  const bf16_t* w2b = (const bf16_t*)(ws + OFF_W2);
  const bf16_t* GTb = (const bf16_t*)(ws + OFF_GT) + (size_t)b * 8192;

  // ---- prologue: stage sp tile to LDS; hoist all n-invariants to registers ----
  {
    f32x4 a0 = *(const f32x4*)(spg + t * 8);
    f32x4 a1 = *(const f32x4*)(spg + t * 8 + 4);
    *(f32x4*)(spL + t * 8)     = a0;
    *(f32x4*)(spL + t * 8 + 4) = a1;
  }
  bf16x8 dpr[4];                         // dp[mt*16+r16][(mh*4+ks)*32+g*8 ..]
  #pragma unroll
  for (int ks = 0; ks < 4; ks++)
    dpr[ks] = g_ld8(dp + (mt * 16 + r16) * 256 + (mh * 4 + ks) * 32 + g * 8);
  bf16x8 w2r[4][8];                      // w2 rows o=(mh*4+ot)*16+r16, all 8 k-slices
  #pragma unroll
  for (int ot = 0; ot < 4; ot++)
    #pragma unroll
    for (int ks = 0; ks < 8; ks++)
      w2r[ot][ks] = g_ld8(w2b + ((mh * 4 + ot) * 16 + r16) * 256 + ks * 32 + g * 8);
  bf16x8 gtr[4];                         // GT rows kc=mt*16+r16
  #pragma unroll
  for (int ks = 0; ks < 4; ks++)
    gtr[ks] = g_ld8(GTb + (mt * 16 + r16) * 128 + ks * 32 + g * 8);
  f32x4 b2v[4];
  #pragma unroll
  for (int ot = 0; ot < 4; ot++)
    b2v[ot] = *(const f32x4*)(b2 + (mh * 4 + ot) * 16 + g * 4);
  f32x4 cvv = *(const f32x4*)((const float*)(ws + OFF_C) + b * 64 + mt * 16 + g * 4);
  f32x4 z = {0.f, 0.f, 0.f, 0.f};

  __syncthreads();   // spL ready

  // build(0) into h1[0]: h1[m][k] = relu(sp[0][k] + dp[m][k])
  {
    int row = mt * 16 + r16;
    #pragma unroll
    for (int ks = 0; ks < 4; ks++) {
      int k = (mh * 4 + ks) * 32 + g * 8;
      f32x4 s0 = *(const f32x4*)(spL + k);
      f32x4 s1 = *(const f32x4*)(spL + k + 4);
      bf16x8 hv;
      #pragma unroll
      for (int j = 0; j < 8; j++) {
        float v = (float)dpr[ks][j] + (j < 4 ? s0[j] : s1[j - 4]);
        hv[j] = (bf16_t)fmaxf(v, 0.f);
      }
      lds_st8(h1[0], row, k, 512, hv);
    }
  }
  __syncthreads();   // h1[0] ready

  float* ob_base = out + 262144u + ((size_t)(b * 64 + nq * 16)) * 4096u;

  for (int nn = 0; nn < 16; ++nn) {
    int cur = nn & 1, nxt = cur ^ 1;

    // 1. build h1 for nn+1 (writes h1[nxt]; nobody reads h1[nxt] until after barrier)
    if (nn < 15) {
      int row = mt * 16 + r16;
      const float* spn = spL + (nn + 1) * 256;
      #pragma unroll
      for (int ks = 0; ks < 4; ks++) {
        int k = (mh * 4 + ks) * 32 + g * 8;
        f32x4 s0 = *(const f32x4*)(spn + k);
        f32x4 s1 = *(const f32x4*)(spn + k + 4);
        bf16x8 hv;
        #pragma unroll
        for (int j = 0; j < 8; j++) {
          float v = (float)dpr[ks][j] + (j < 4 ? s0[j] : s1[j - 4]);
          hv[j] = (bf16_t)fmaxf(v, 0.f);
        }
        lds_st8(h1[nxt], row, k, 512, hv);
      }
    }

    // 2. GEMM1(nn): h2[m][o] = relu(sum_k h1[m][k]*w2[o][k] + b2[o])
    //    wave (mt, mh): B = h1 rows mt*16.., A = w2 regs (4 o-tiles), reuse 4x per LDS read
    f32x4 acc[4];
    #pragma unroll
    for (int ot = 0; ot < 4; ot++) acc[ot] = z;
    #pragma unroll
    for (int ks = 0; ks < 8; ks++) {
      bf16x8 bb = lds_ld8(h1[cur], mt * 16 + r16, ks * 32 + g * 8, 512);
      __builtin_amdgcn_s_setprio(1);
      #pragma unroll
      for (int ot = 0; ot < 4; ot++) acc[ot] = mfma16(w2r[ot][ks], bb, acc[ot]);
      __builtin_amdgcn_s_setprio(0);
    }

    // 3. h2 write (D: col=m=r16, row=o j-consec -> vectorized st4)
    #pragma unroll
    for (int ot = 0; ot < 4; ot++) {
      int o0 = (mh * 4 + ot) * 16 + g * 4;
      bf16x4 pk;
      #pragma unroll
      for (int j = 0; j < 4; j++) pk[j] = (bf16_t)fmaxf(acc[ot][j] + b2v[ot][j], 0.f);
      lds_st4(h2[cur], mt * 16 + r16, o0, 256, pk);
    }

    __syncthreads();   // the ONE barrier: h1[nxt] + h2[cur] complete

    // 4. GEMM3(nn): arrow[m][kc] = sum_o h2[m][o]*GT[kc][o] + c[kc]
    //    wave (kct=mt, mh): A = GT regs, B = h2 rows (mh*2+i)*16..
    f32x4 acc2[2];
    #pragma unroll
    for (int i = 0; i < 2; i++) acc2[i] = z;
    #pragma unroll
    for (int ks = 0; ks < 4; ks++) {
      __builtin_amdgcn_s_setprio(1);
      #pragma unroll
      for (int i = 0; i < 2; i++) {
        bf16x8 bb = lds_ld8(h2[cur], (mh * 2 + i) * 16 + r16, ks * 32 + g * 8, 256);
        acc2[i] = mfma16(gtr[ks], bb, acc2[i]);
      }
      __builtin_amdgcn_s_setprio(0);
    }
    float* ob = ob_base + (size_t)nn * 4096u;
    #pragma unroll
    for (int i = 0; i < 2; i++) {
      int m = (mh * 2 + i) * 16 + r16;
      *(f32x4*)(ob + m * 64 + mt * 16 + g * 4) = acc2[i] + cvv;
    }
    // no barrier here: next iteration writes h1[cur]/h2[nxt], disjoint from h2[cur] reads
  }
}

// ======================= launch ========================================================
extern "C" void kernel_launch(void* const* d_in, const int* in_sizes, int n_in,
                              void* d_out, int out_size, void* d_ws, size_t ws_size,
                              hipStream_t stream) {
  (void)in_sizes; (void)n_in; (void)out_size; (void)ws_size;
  const float* x    = (const float*)d_in[0];
  const float* wsrc = (const float*)d_in[1];
  const float* bsrc = (const float*)d_in[2];
  const float* wdst = (const float*)d_in[3];
  const float* bdst = (const float*)d_in[4];
  const float* warr = (const float*)d_in[5];
  const float* barr = (const float*)d_in[6];
  const float* w1   = (const float*)d_in[7];
  const float* b1   = (const float*)d_in[8];
  const float* w2   = (const float*)d_in[9];
  const float* b2   = (const float*)d_in[10];
  const float* w3   = (const float*)d_in[11];
  const float* b3   = (const float*)d_in[12];
  char* ws = (char*)d_ws;
  float* out = (float*)d_out;

  hipLaunchKernelGGL(k0_prep, dim3(64), dim3(256), 0, stream, wsrc, wdst, warr, w1, w2, w3, ws);
  hipLaunchKernelGGL(k1_fproj, dim3(192), dim3(256), 0, stream, x, bsrc, bdst, barr, ws);
  hipLaunchKernelGGL(k2_pre, dim3(256), dim3(256), 0, stream, b1, b3, ws, out);
  hipLaunchKernelGGL(k3_main, dim3(256), dim3(512), 0, stream, b2, ws, out);
}